// Round 4
// baseline (162.968 us; speedup 1.0000x reference)
//
#include <hip/hip_runtime.h>
#include <math.h>

#define BDIM 256
#define NSTREAMB 1769          // 85 + 337 + 1347 single-pass streaming blocks
#define NCELLB 334             // 16 + 64 + 254 cell blocks
#define NBLK_A (NSTREAMB + NCELLB)   // 2103
#define NB_IGNORE 336          // 16 + 64 + 256 (per image,chunk)
#define TCAP 512

// Anchors per layer: l0 = mask[6,7,8], l1 = [3,4,5], l2 = [0,1,2]
__device__ __constant__ float c_aw[3][3] = {{116.f,156.f,373.f},{30.f,62.f,59.f},{10.f,16.f,33.f}};
__device__ __constant__ float c_ah[3][3] = {{90.f,198.f,326.f},{61.f,45.f,119.f},{13.f,30.f,23.f}};

// ws layout — NO pre-zero needed (every slot written unconditionally):
//   accq7  @0       3 dbl   zeroed by A block 0; atomicAdd'ed by B blocks
//   done   @24      1 int   zeroed by A block 0
//   slotS  @64      1769 dbl  per-streaming-block S_all partial
//   slotC  @14336   334*6 dbl per-cell-block partials (sub,xy,wh,conf,obj,s1)
//   countB @30720   334 int   per-cell-block target count
//   cidxB  @32768   334*256 int   layer-local cell index of each target
//   tboxB  @375296  334*256 f4    compacted targets (block-major)
//   pbox   @1742848 85176 f4
//   noobj  @3105664 85176 f
// Layer cell bases: {0, 4056, 20280}; layer cell-block bases: {0, 16, 80};
// layer streaming-block bases: {0, 85, 422}.

__device__ __forceinline__ float bce_fast(float z, float x) {
    float t = __expf(-fabsf(x));
    return fmaxf(x, 0.f) - x * z + __logf(1.f + t);
}
__device__ __forceinline__ float bce4(const float4& z, const float4& x) {
    return bce_fast(z.x, x.x) + bce_fast(z.y, x.y)
         + bce_fast(z.z, x.z) + bce_fast(z.w, x.w);
}

// ---- Kernel A: streaming S_all + cell pass (slot writes, no atomics) ------
__global__ __launch_bounds__(BDIM) void mega_a(
    const float* __restrict__ o0, const float* __restrict__ l0,
    const float* __restrict__ o1, const float* __restrict__ l1,
    const float* __restrict__ o2, const float* __restrict__ l2,
    double* __restrict__ accq7, int* __restrict__ done,
    double* __restrict__ slotS, double* __restrict__ slotC,
    int* __restrict__ countB, int* __restrict__ cidxB,
    float4* __restrict__ tboxB, float4* __restrict__ pbox,
    float* __restrict__ noobj)
{
    if (blockIdx.x < NSTREAMB) {
        if (blockIdx.x == 0 && threadIdx.x == 0) {
            accq7[0] = 0.0; accq7[1] = 0.0; accq7[2] = 0.0; *done = 0;
        }
        int blk0, n4;
        const float4 *O4, *L4;
        if (blockIdx.x < 85)       { blk0=0;   n4=86190;   O4=(const float4*)o0; L4=(const float4*)l0; }
        else if (blockIdx.x < 422) { blk0=85;  n4=344760;  O4=(const float4*)o1; L4=(const float4*)l1; }
        else                       { blk0=422; n4=1379040; O4=(const float4*)o2; L4=(const float4*)l2; }

        int rb   = (int)blockIdx.x - blk0;
        int base = rb * (BDIM * 4) + (int)threadIdx.x;
        float s0 = 0.f, s1 = 0.f, s2 = 0.f, s3 = 0.f;
        if ((rb + 1) * (BDIM * 4) <= n4) {
            float4 a0 = O4[base];          float4 b0 = L4[base];
            float4 a1 = O4[base +   BDIM]; float4 b1 = L4[base +   BDIM];
            float4 a2 = O4[base + 2*BDIM]; float4 b2 = L4[base + 2*BDIM];
            float4 a3 = O4[base + 3*BDIM]; float4 b3 = L4[base + 3*BDIM];
            s0 = bce4(b0, a0); s1 = bce4(b1, a1);
            s2 = bce4(b2, a2); s3 = bce4(b3, a3);
        } else {
            #pragma unroll
            for (int k = 0; k < 4; k++) {
                int j = base + k * BDIM;
                if (j < n4) { float4 a = O4[j], b = L4[j]; s0 += bce4(b, a); }
            }
        }
        float s = (s0 + s1) + (s2 + s3);
        __shared__ float sb[4];
        #pragma unroll
        for (int off = 32; off > 0; off >>= 1) s += __shfl_down(s, off, 64);
        if ((threadIdx.x & 63) == 0) sb[threadIdx.x >> 6] = s;
        __syncthreads();
        if (threadIdx.x == 0)
            slotS[blockIdx.x] = (double)sb[0] + (double)sb[1]
                              + (double)sb[2] + (double)sb[3];
        return;
    }

    // ---- cell role ---------------------------------------------------------
    int cb = blockIdx.x - NSTREAMB;       // 0..333
    int layer, cblk0;
    if (cb < 16)      { layer = 0; cblk0 = 0; }
    else if (cb < 80) { layer = 1; cblk0 = 16; }
    else              { layer = 2; cblk0 = 80; }
    const int g     = (layer == 0) ? 13 : (layer == 1) ? 26 : 52;
    const int Nlimg = g * g * 3;
    const int Cl    = 8 * Nlimg;
    const int cbase = (layer == 0) ? 0 : (layer == 1) ? 4056 : 20280;
    const float* O  = (layer == 0) ? o0 : (layer == 1) ? o1 : o2;
    const float* L  = (layer == 0) ? l0 : (layer == 1) ? l1 : l2;
    const float gf  = (float)g;
    const float inp = gf * 32.f;

    int  cell = (cb - cblk0) * BDIM + (int)threadIdx.x;
    bool live = (cell < Cl);
    float s_sub=0.f, s_xy=0.f, s_wh=0.f, s_conf=0.f, s_obj=0.f, s_s1=0.f;
    bool  f = false;
    float tlx=0.f, tly=0.f, tlw=0.f, tlh=0.f;
    if (live) {
        const float* op = O + (size_t)cell * 85;
        const float* lp = L + (size_t)cell * 85;
        float x0=op[0], x1=op[1], x2=op[2], x3=op[3], x4=op[4];
        float lx=lp[0], ly=lp[1], lw=lp[2], lh=lp[3], lobj=lp[4];
        int a  = cell % 3;
        int xi = (cell / 3) % g;
        int yi = (cell / (3 * g)) % g;
        float aw = c_aw[layer][a], ah = c_ah[layer][a];

        float c4 = bce_fast(lobj, x4);
        s_sub  = bce_fast(lx,x0) + bce_fast(ly,x1)
               + bce_fast(lw,x2) + bce_fast(lh,x3) + c4;
        s_conf = c4;
        s_obj  = lobj;
        s_xy   = bce_fast(lx*gf - (float)xi, x0) + bce_fast(ly*gf - (float)yi, x1);

        // accurate exp/sigmoid: pbox feeds a 0.5-threshold compare
        float px = (1.f/(1.f+expf(-x0)) + (float)xi) / gf;
        float py = (1.f/(1.f+expf(-x1)) + (float)yi) / gf;
        float pw = expf(x2) * aw / inp;
        float ph = expf(x3) * ah / inp;
        pbox[cbase + cell]  = make_float4(px, py, pw, ph);
        noobj[cbase + cell] = 1.f - lobj;

        if (lobj != 0.f) {
            float bls = 2.f - lw * lh;
            s_s1 = lobj * bls;
            float dw = logf(lw * inp / aw) - x2;
            float dh = logf(lh * inp / ah) - x3;
            s_wh = lobj * bls * 0.5f * (dw * dw + dh * dh);
            f = true; tlx = lx; tly = ly; tlw = lw; tlh = lh;
        }
    }

    // deterministic in-block compaction (no global atomics, no init needed)
    unsigned long long m = __ballot(f);
    int lane = threadIdx.x & 63, wid = threadIdx.x >> 6;
    __shared__ int wcnt[4];
    if (lane == 0) wcnt[wid] = __popcll(m);
    int pos = __popcll(m & ((1ull << lane) - 1));
    __syncthreads();
    int wbase = 0;
    #pragma unroll
    for (int w = 0; w < 4; w++) if (w < wid) wbase += wcnt[w];
    if (f) {
        int p = cb * BDIM + wbase + pos;
        tboxB[p] = make_float4(tlx, tly, tlw, tlh);
        cidxB[p] = cell;
    }
    if (threadIdx.x == 0)
        countB[cb] = wcnt[0] + wcnt[1] + wcnt[2] + wcnt[3];

    __shared__ float sb6[6][4];
    float v[6] = {s_sub, s_xy, s_wh, s_conf, s_obj, s_s1};
    #pragma unroll
    for (int q = 0; q < 6; q++) {
        float x = v[q];
        #pragma unroll
        for (int off = 32; off > 0; off >>= 1) x += __shfl_down(x, off, 64);
        if ((threadIdx.x & 63) == 0) sb6[q][threadIdx.x >> 6] = x;
    }
    __syncthreads();
    if (threadIdx.x < 6) {
        int q = threadIdx.x;
        slotC[cb * 6 + q] = (double)sb6[q][0] + (double)sb6[q][1]
                          + (double)sb6[q][2] + (double)sb6[q][3];
    }
}

// ---- Kernel B: ignore-mask + last-block slot reduction + finalize ---------
__global__ __launch_bounds__(BDIM) void ignore_fin(
    double* __restrict__ accq7, int* __restrict__ done,
    const double* __restrict__ slotS, const double* __restrict__ slotC,
    const int* __restrict__ countB, const int* __restrict__ cidxB,
    const float4* __restrict__ tboxB, const float4* __restrict__ pbox,
    const float* __restrict__ noobj, float* __restrict__ out)
{
    int layer, img, chunk;
    if (blockIdx.x < 16)      { layer = 0; img = blockIdx.x >> 1; chunk = blockIdx.x & 1; }
    else if (blockIdx.x < 80) { int t = blockIdx.x - 16; layer = 1; img = t >> 3; chunk = t & 7; }
    else                      { int t = blockIdx.x - 80; layer = 2; img = t >> 5; chunk = t & 31; }
    const int g     = (layer == 0) ? 13 : (layer == 1) ? 26 : 52;
    const int Nlimg = g * g * 3;
    const int cbase = (layer == 0) ? 0 : (layer == 1) ? 4056 : 20280;
    const int cblk0 = (layer == 0) ? 0 : (layer == 1) ? 16 : 80;

    int ci = chunk * BDIM + (int)threadIdx.x;
    bool live = (ci < Nlimg);
    int cell = cbase + img * Nlimg + (live ? ci : 0);

    float pminx=0, pmaxx=0, pminy=0, pmaxy=0, a1=0, nb=0;
    if (live) {
        float4 p = pbox[cell];
        pminx = p.x - p.z*0.5f; pmaxx = p.x + p.z*0.5f;
        pminy = p.y - p.w*0.5f; pmaxy = p.y + p.w*0.5f;
        a1 = p.z * p.w;
        nb = noobj[cell];
    }

    // gather this image's targets from its covering cell blocks' compact lists
    int b0 = cblk0 + (img * Nlimg) / BDIM;
    int b1 = cblk0 + ((img + 1) * Nlimg - 1) / BDIM;
    int nbk = b1 - b0 + 1;                 // <= 33

    __shared__ int    sCnt[40];
    __shared__ int    sN;
    __shared__ float4 sT[TCAP];
    for (int i = threadIdx.x; i < nbk; i += BDIM) sCnt[i] = countB[b0 + i];
    if (threadIdx.x == 0) sN = 0;

    float best = -1.f;                     // replicates where(valid, iou, -1)
    bool donef = !live;

#define IOU_SCAN(TN)                                                         \
    if (!donef) {                                                            \
        for (int j = 0; j < (TN); j++) {                                     \
            float4 t = sT[j];                                                \
            float hw = t.z*0.5f, hh = t.w*0.5f;                              \
            /* reference uses maximum for BOTH mins and maxes */             \
            float imnx = fmaxf(pminx, t.x - hw);                             \
            float imxx = fmaxf(pmaxx, t.x + hw);                             \
            float imny = fmaxf(pminy, t.y - hh);                             \
            float imxy = fmaxf(pmaxy, t.y + hh);                             \
            float iw = fmaxf(imxx - imnx, 0.f);                              \
            float ih = fmaxf(imxy - imny, 0.f);                              \
            float inter = iw * ih;                                           \
            float iou = inter / (a1 + t.z*t.w - inter);                      \
            best = fmaxf(best, iou);                                         \
            if (best >= 0.5f) { donef = true; break; }                       \
        }                                                                    \
    }

    for (int bi = 0; bi < nbk; ++bi) {
        __syncthreads();                   // sCnt ready / sN settled
        int n = sCnt[bi];
        if (sN + n > TCAP) {               // uniform flush (rare)
            int tn = sN;
            IOU_SCAN(tn);
            __syncthreads();
            if (threadIdx.x == 0) sN = 0;
            __syncthreads();
        }
        int gbase = (b0 + bi) * BDIM;
        for (int i = threadIdx.x; i < n; i += BDIM) {
            int cidx = cidxB[gbase + i];
            if (cidx / Nlimg == img) {
                int p = atomicAdd(&sN, 1);
                sT[p] = tboxB[gbase + i];
            }
        }
    }
    __syncthreads();
    {
        int tn = sN;
        IOU_SCAN(tn);
    }

    float v = (live && best < 0.5f) ? nb : 0.f;
    __shared__ float sbr[4];
    #pragma unroll
    for (int off = 32; off > 0; off >>= 1) v += __shfl_down(v, off, 64);
    if ((threadIdx.x & 63) == 0) sbr[threadIdx.x >> 6] = v;
    __syncthreads();
    __shared__ int isLast;
    if (threadIdx.x == 0) {
        double t = (double)sbr[0] + (double)sbr[1] + (double)sbr[2] + (double)sbr[3];
        atomicAdd(&accq7[layer], t);
        __threadfence();
        int old = atomicAdd(done, 1);
        isLast = (old == NB_IGNORE - 1) ? 1 : 0;
    }
    __syncthreads();
    if (!isLast) return;

    // ---- last block: reduce all slots (prev-dispatch writes: plain loads OK;
    //      accq7 written during THIS dispatch: fenced + agent-scope loads) ----
    __threadfence();
    double qs0=0, qs1=0, qs2=0;            // q0 per layer (streaming S_all)
    for (int i = threadIdx.x; i < NSTREAMB; i += BDIM) {
        double x = slotS[i];
        if (i < 85) qs0 += x; else if (i < 422) qs1 += x; else qs2 += x;
    }
    double c00=0,c01=0,c02=0,c03=0,c04=0,c05=0;
    double c10=0,c11=0,c12=0,c13=0,c14=0,c15=0;
    double c20=0,c21=0,c22=0,c23=0,c24=0,c25=0;
#define CSUM(LO, HI, A0,A1,A2,A3,A4,A5)                                      \
    for (int i = (LO)*6 + (int)threadIdx.x; i < (HI)*6; i += BDIM) {         \
        int q = i % 6; double x = slotC[i];                                  \
        if      (q == 0) A0 += x; else if (q == 1) A1 += x;                  \
        else if (q == 2) A2 += x; else if (q == 3) A3 += x;                  \
        else if (q == 4) A4 += x; else             A5 += x;                  \
    }
    CSUM(0,   16,  c00,c01,c02,c03,c04,c05)
    CSUM(16,  80,  c10,c11,c12,c13,c14,c15)
    CSUM(80,  334, c20,c21,c22,c23,c24,c25)

    __shared__ double dsum[21][4];
    {
        double vals[21] = {qs0,qs1,qs2,
                           c00,c01,c02,c03,c04,c05,
                           c10,c11,c12,c13,c14,c15,
                           c20,c21,c22,c23,c24,c25};
        int lane = threadIdx.x & 63, wid = threadIdx.x >> 6;
        #pragma unroll
        for (int k = 0; k < 21; k++) {
            double r = vals[k];
            #pragma unroll
            for (int off = 32; off > 0; off >>= 1) r += __shfl_down(r, off, 64);
            if (lane == 0) dsum[k][wid] = r;
        }
    }
    __syncthreads();
    if (threadIdx.x == 0) {
        double loss = 0.0;
        const int gsz[3] = {13, 26, 52};
        for (int l = 0; l < 3; l++) {
            double C = 8.0 * gsz[l] * gsz[l] * 3.0;
            double Q0 = dsum[l][0] + dsum[l][1] + dsum[l][2] + dsum[l][3];
            double Qs[6];
            for (int j = 0; j < 6; j++) {
                int k = 3 + l * 6 + j;
                Qs[j] = dsum[k][0] + dsum[k][1] + dsum[k][2] + dsum[k][3];
            }
            double q7 = __hip_atomic_load(&accq7[l], __ATOMIC_RELAXED,
                                          __HIP_MEMORY_SCOPE_AGENT);
            double cls = (Q0 - Qs[0]) / (C * 80.0);
            loss += ( (Qs[1]/(C*2.0))*Qs[5] + Qs[2]
                    + (Qs[3]/C)*(Qs[4]+q7) + cls*Qs[4] ) / 8.0;
        }
        out[0] = (float)loss;
    }
}

extern "C" void kernel_launch(void* const* d_in, const int* in_sizes, int n_in,
                              void* d_out, int out_size, void* d_ws, size_t ws_size,
                              hipStream_t stream)
{
    const float* o0 = (const float*)d_in[0];
    const float* l0 = (const float*)d_in[1];
    const float* o1 = (const float*)d_in[2];
    const float* l1 = (const float*)d_in[3];
    const float* o2 = (const float*)d_in[4];
    const float* l2 = (const float*)d_in[5];

    double* accq7  = (double*)d_ws;
    int*    done   = (int*)((char*)d_ws + 24);
    double* slotS  = (double*)((char*)d_ws + 64);
    double* slotC  = (double*)((char*)d_ws + 14336);
    int*    countB = (int*)((char*)d_ws + 30720);
    int*    cidxB  = (int*)((char*)d_ws + 32768);
    float4* tboxB  = (float4*)((char*)d_ws + 375296);
    float4* pbox   = (float4*)((char*)d_ws + 1742848);
    float*  noobj  = (float*)((char*)d_ws + 3105664);

    mega_a<<<NBLK_A, BDIM, 0, stream>>>(o0, l0, o1, l1, o2, l2,
                                        accq7, done, slotS, slotC,
                                        countB, cidxB, tboxB, pbox, noobj);
    ignore_fin<<<NB_IGNORE, BDIM, 0, stream>>>(accq7, done, slotS, slotC,
                                               countB, cidxB, tboxB, pbox,
                                               noobj, (float*)d_out);
}

// Round 5
// 151.864 us; speedup vs baseline: 1.0731x; 1.0731x over previous
//
#include <hip/hip_runtime.h>
#include <math.h>

#define BDIM 256
#define NSTREAMB 1769          // 85 + 337 + 1347 single-pass streaming blocks
#define NCELLB 334             // 16 + 64 + 254 cell blocks
#define NBLK_A (NSTREAMB + NCELLB)   // 2103
#define NB_IGNORE 336          // 16 + 64 + 256 (per image,chunk)
#define SCAP 1024              // target capacity per image (mean ~162, 68 sigma)

// Anchors per layer: l0 = mask[6,7,8], l1 = [3,4,5], l2 = [0,1,2]
__device__ __constant__ float c_aw[3][3] = {{116.f,156.f,373.f},{30.f,62.f,59.f},{10.f,16.f,33.f}};
__device__ __constant__ float c_ah[3][3] = {{90.f,198.f,326.f},{61.f,45.f,119.f},{13.f,30.f,23.f}};

// ws layout — NO pre-zero needed:
//   accq7 @0      3 dbl  zeroed by A block 0 (stream-ordered before B)
//   done  @24     1 int  zeroed by A block 0
//   slotS @64     1769 dbl  per-streaming-block S_all partial (unconditional)
//   slotC @14336  334*6 dbl per-cell-block partials (sub,xy,wh,conf,obj,s1)
//   pbox  @30720  85176 f4  decoded pred boxes
//   noobj @1393664 85176 f  1-obj  (0.0 marks a target cell — exact)
// Layer cell bases {0,4056,20280}; streaming-block bases {0,85,422}.

__device__ __forceinline__ float bce_fast(float z, float x) {
    float t = __expf(-fabsf(x));
    return fmaxf(x, 0.f) - x * z + __logf(1.f + t);
}
__device__ __forceinline__ float bce4(const float4& z, const float4& x) {
    return bce_fast(z.x, x.x) + bce_fast(z.y, x.y)
         + bce_fast(z.z, x.z) + bce_fast(z.w, x.w);
}

// ---- Kernel A: streaming S_all + cell pass (slot writes, no atomics) ------
__global__ __launch_bounds__(BDIM) void mega_a(
    const float* __restrict__ o0, const float* __restrict__ l0,
    const float* __restrict__ o1, const float* __restrict__ l1,
    const float* __restrict__ o2, const float* __restrict__ l2,
    double* __restrict__ accq7, int* __restrict__ done,
    double* __restrict__ slotS, double* __restrict__ slotC,
    float4* __restrict__ pbox, float* __restrict__ noobj)
{
    if (blockIdx.x < NSTREAMB) {
        if (blockIdx.x == 0 && threadIdx.x == 0) {
            accq7[0] = 0.0; accq7[1] = 0.0; accq7[2] = 0.0; *done = 0;
        }
        int blk0, n4;
        const float4 *O4, *L4;
        if (blockIdx.x < 85)       { blk0=0;   n4=86190;   O4=(const float4*)o0; L4=(const float4*)l0; }
        else if (blockIdx.x < 422) { blk0=85;  n4=344760;  O4=(const float4*)o1; L4=(const float4*)l1; }
        else                       { blk0=422; n4=1379040; O4=(const float4*)o2; L4=(const float4*)l2; }

        int rb   = (int)blockIdx.x - blk0;
        int base = rb * (BDIM * 4) + (int)threadIdx.x;
        float s0 = 0.f, s1 = 0.f, s2 = 0.f, s3 = 0.f;
        if ((rb + 1) * (BDIM * 4) <= n4) {
            float4 a0 = O4[base];          float4 b0 = L4[base];
            float4 a1 = O4[base +   BDIM]; float4 b1 = L4[base +   BDIM];
            float4 a2 = O4[base + 2*BDIM]; float4 b2 = L4[base + 2*BDIM];
            float4 a3 = O4[base + 3*BDIM]; float4 b3 = L4[base + 3*BDIM];
            s0 = bce4(b0, a0); s1 = bce4(b1, a1);
            s2 = bce4(b2, a2); s3 = bce4(b3, a3);
        } else {
            #pragma unroll
            for (int k = 0; k < 4; k++) {
                int j = base + k * BDIM;
                if (j < n4) { float4 a = O4[j], b = L4[j]; s0 += bce4(b, a); }
            }
        }
        float s = (s0 + s1) + (s2 + s3);
        __shared__ float sb[4];
        #pragma unroll
        for (int off = 32; off > 0; off >>= 1) s += __shfl_down(s, off, 64);
        if ((threadIdx.x & 63) == 0) sb[threadIdx.x >> 6] = s;
        __syncthreads();
        if (threadIdx.x == 0)
            slotS[blockIdx.x] = (double)sb[0] + (double)sb[1]
                              + (double)sb[2] + (double)sb[3];
        return;
    }

    // ---- cell role: ch0..4 losses + pbox/noobj ----------------------------
    int cb = blockIdx.x - NSTREAMB;       // 0..333
    int layer, cblk0;
    if (cb < 16)      { layer = 0; cblk0 = 0; }
    else if (cb < 80) { layer = 1; cblk0 = 16; }
    else              { layer = 2; cblk0 = 80; }
    const int g     = (layer == 0) ? 13 : (layer == 1) ? 26 : 52;
    const int Nlimg = g * g * 3;
    const int Cl    = 8 * Nlimg;
    const int cbase = (layer == 0) ? 0 : (layer == 1) ? 4056 : 20280;
    const float* O  = (layer == 0) ? o0 : (layer == 1) ? o1 : o2;
    const float* L  = (layer == 0) ? l0 : (layer == 1) ? l1 : l2;
    const float gf  = (float)g;
    const float inp = gf * 32.f;

    int  cell = (cb - cblk0) * BDIM + (int)threadIdx.x;
    bool live = (cell < Cl);
    float s_sub=0.f, s_xy=0.f, s_wh=0.f, s_conf=0.f, s_obj=0.f, s_s1=0.f;
    if (live) {
        const float* op = O + (size_t)cell * 85;
        const float* lp = L + (size_t)cell * 85;
        float x0=op[0], x1=op[1], x2=op[2], x3=op[3], x4=op[4];
        float lx=lp[0], ly=lp[1], lw=lp[2], lh=lp[3], lobj=lp[4];
        int a  = cell % 3;
        int xi = (cell / 3) % g;
        int yi = (cell / (3 * g)) % g;
        float aw = c_aw[layer][a], ah = c_ah[layer][a];

        float c4 = bce_fast(lobj, x4);
        s_sub  = bce_fast(lx,x0) + bce_fast(ly,x1)
               + bce_fast(lw,x2) + bce_fast(lh,x3) + c4;
        s_conf = c4;
        s_obj  = lobj;
        s_xy   = bce_fast(lx*gf - (float)xi, x0) + bce_fast(ly*gf - (float)yi, x1);

        // accurate exp/sigmoid: pbox feeds a 0.5-threshold compare
        float px = (1.f/(1.f+expf(-x0)) + (float)xi) / gf;
        float py = (1.f/(1.f+expf(-x1)) + (float)yi) / gf;
        float pw = expf(x2) * aw / inp;
        float ph = expf(x3) * ah / inp;
        pbox[cbase + cell]  = make_float4(px, py, pw, ph);
        noobj[cbase + cell] = 1.f - lobj;

        if (lobj != 0.f) {
            float bls = 2.f - lw * lh;
            s_s1 = lobj * bls;
            float dw = logf(lw * inp / aw) - x2;
            float dh = logf(lh * inp / ah) - x3;
            s_wh = lobj * bls * 0.5f * (dw * dw + dh * dh);
        }
    }

    __shared__ float sb6[6][4];
    float v[6] = {s_sub, s_xy, s_wh, s_conf, s_obj, s_s1};
    #pragma unroll
    for (int q = 0; q < 6; q++) {
        float x = v[q];
        #pragma unroll
        for (int off = 32; off > 0; off >>= 1) x += __shfl_down(x, off, 64);
        if ((threadIdx.x & 63) == 0) sb6[q][threadIdx.x >> 6] = x;
    }
    __syncthreads();
    if (threadIdx.x < 6) {
        int q = threadIdx.x;
        slotC[cb * 6 + q] = (double)sb6[q][0] + (double)sb6[q][1]
                          + (double)sb6[q][2] + (double)sb6[q][3];
    }
}

// ---- Kernel B: self-contained ignore-mask + last-block finalize -----------
// Target discovery: scan this image's dense noobj strip (coalesced, L2-hot),
// compact cells with noobj==0 (exact: obj is 0/1), fetch boxes from raw labels.
__global__ __launch_bounds__(BDIM) void ignore_fin(
    const float* __restrict__ l0, const float* __restrict__ l1,
    const float* __restrict__ l2,
    double* __restrict__ accq7, int* __restrict__ done,
    const double* __restrict__ slotS, const double* __restrict__ slotC,
    const float4* __restrict__ pbox, const float* __restrict__ noobj,
    float* __restrict__ out)
{
    int layer, img, chunk;
    if (blockIdx.x < 16)      { layer = 0; img = blockIdx.x >> 1; chunk = blockIdx.x & 1; }
    else if (blockIdx.x < 80) { int t = blockIdx.x - 16; layer = 1; img = t >> 3; chunk = t & 7; }
    else                      { int t = blockIdx.x - 80; layer = 2; img = t >> 5; chunk = t & 31; }
    const int g     = (layer == 0) ? 13 : (layer == 1) ? 26 : 52;
    const int Nlimg = g * g * 3;
    const int cbase = (layer == 0) ? 0 : (layer == 1) ? 4056 : 20280;
    const float* L  = (layer == 0) ? l0 : (layer == 1) ? l1 : l2;

    int ci = chunk * BDIM + (int)threadIdx.x;
    bool live = (ci < Nlimg);
    int cell = cbase + img * Nlimg + (live ? ci : 0);

    float pminx=0, pmaxx=0, pminy=0, pmaxy=0, a1=0, nb=0;
    if (live) {
        float4 p = pbox[cell];
        pminx = p.x - p.z*0.5f; pmaxx = p.x + p.z*0.5f;
        pminy = p.y - p.w*0.5f; pmaxy = p.y + p.w*0.5f;
        a1 = p.z * p.w;
        nb = noobj[cell];
    }

    // -- discover targets: noobj==0.0f marks obj!=0 cells (exact 1-1=0) -----
    __shared__ int    sIdx[SCAP];
    __shared__ int    sN;
    __shared__ float4 sT[SCAP];
    if (threadIdx.x == 0) sN = 0;
    __syncthreads();
    const float* nob = noobj + cbase + img * Nlimg;
    for (int i = threadIdx.x; i < Nlimg; i += BDIM) {
        if (nob[i] == 0.0f) {
            int p = atomicAdd(&sN, 1);
            if (p < SCAP) sIdx[p] = i;
        }
    }
    __syncthreads();
    int n = min(sN, SCAP);
    for (int i = threadIdx.x; i < n; i += BDIM) {
        const float* lp = L + (size_t)(img * Nlimg + sIdx[i]) * 85;
        sT[i] = make_float4(lp[0], lp[1], lp[2], lp[3]);
    }
    __syncthreads();

    float best = -1.f;                     // replicates where(valid, iou, -1)
    if (live) {
        for (int j = 0; j < n; j++) {
            float4 t = sT[j];
            float hw = t.z*0.5f, hh = t.w*0.5f;
            // reference uses maximum for BOTH mins and maxes (replicated bug)
            float imnx = fmaxf(pminx, t.x - hw);
            float imxx = fmaxf(pmaxx, t.x + hw);
            float imny = fmaxf(pminy, t.y - hh);
            float imxy = fmaxf(pmaxy, t.y + hh);
            float iw = fmaxf(imxx - imnx, 0.f);
            float ih = fmaxf(imxy - imny, 0.f);
            float inter = iw * ih;
            float iou = inter / (a1 + t.z*t.w - inter);
            best = fmaxf(best, iou);
            if (best >= 0.5f) break;       // max is exact & order-independent
        }
    }

    float v = (live && best < 0.5f) ? nb : 0.f;
    __shared__ float sbr[4];
    #pragma unroll
    for (int off = 32; off > 0; off >>= 1) v += __shfl_down(v, off, 64);
    if ((threadIdx.x & 63) == 0) sbr[threadIdx.x >> 6] = v;
    __syncthreads();
    __shared__ int isLast;
    if (threadIdx.x == 0) {
        double t = (double)sbr[0] + (double)sbr[1] + (double)sbr[2] + (double)sbr[3];
        atomicAdd(&accq7[layer], t);
        __threadfence();
        int old = atomicAdd(done, 1);
        isLast = (old == NB_IGNORE - 1) ? 1 : 0;
    }
    __syncthreads();
    if (!isLast) return;

    // ---- last block: reduce all slots -------------------------------------
    __threadfence();
    double qs0=0, qs1=0, qs2=0;            // q0 per layer (streaming S_all)
    for (int i = threadIdx.x; i < NSTREAMB; i += BDIM) {
        double x = slotS[i];
        if (i < 85) qs0 += x; else if (i < 422) qs1 += x; else qs2 += x;
    }
    double c00=0,c01=0,c02=0,c03=0,c04=0,c05=0;
    double c10=0,c11=0,c12=0,c13=0,c14=0,c15=0;
    double c20=0,c21=0,c22=0,c23=0,c24=0,c25=0;
#define CSUM(LO, HI, A0,A1,A2,A3,A4,A5)                                      \
    for (int i = (LO)*6 + (int)threadIdx.x; i < (HI)*6; i += BDIM) {         \
        int q = i % 6; double x = slotC[i];                                  \
        if      (q == 0) A0 += x; else if (q == 1) A1 += x;                  \
        else if (q == 2) A2 += x; else if (q == 3) A3 += x;                  \
        else if (q == 4) A4 += x; else             A5 += x;                  \
    }
    CSUM(0,   16,  c00,c01,c02,c03,c04,c05)
    CSUM(16,  80,  c10,c11,c12,c13,c14,c15)
    CSUM(80,  334, c20,c21,c22,c23,c24,c25)

    __shared__ double dsum[21][4];
    {
        double vals[21] = {qs0,qs1,qs2,
                           c00,c01,c02,c03,c04,c05,
                           c10,c11,c12,c13,c14,c15,
                           c20,c21,c22,c23,c24,c25};
        int lane = threadIdx.x & 63, wid = threadIdx.x >> 6;
        #pragma unroll
        for (int k = 0; k < 21; k++) {
            double r = vals[k];
            #pragma unroll
            for (int off = 32; off > 0; off >>= 1) r += __shfl_down(r, off, 64);
            if (lane == 0) dsum[k][wid] = r;
        }
    }
    __syncthreads();
    if (threadIdx.x == 0) {
        double loss = 0.0;
        const int gsz[3] = {13, 26, 52};
        for (int l = 0; l < 3; l++) {
            double C = 8.0 * gsz[l] * gsz[l] * 3.0;
            double Q0 = dsum[l][0] + dsum[l][1] + dsum[l][2] + dsum[l][3];
            double Qs[6];
            for (int j = 0; j < 6; j++) {
                int k = 3 + l * 6 + j;
                Qs[j] = dsum[k][0] + dsum[k][1] + dsum[k][2] + dsum[k][3];
            }
            double q7 = __hip_atomic_load(&accq7[l], __ATOMIC_RELAXED,
                                          __HIP_MEMORY_SCOPE_AGENT);
            double cls = (Q0 - Qs[0]) / (C * 80.0);
            loss += ( (Qs[1]/(C*2.0))*Qs[5] + Qs[2]
                    + (Qs[3]/C)*(Qs[4]+q7) + cls*Qs[4] ) / 8.0;
        }
        out[0] = (float)loss;
    }
}

extern "C" void kernel_launch(void* const* d_in, const int* in_sizes, int n_in,
                              void* d_out, int out_size, void* d_ws, size_t ws_size,
                              hipStream_t stream)
{
    const float* o0 = (const float*)d_in[0];
    const float* l0 = (const float*)d_in[1];
    const float* o1 = (const float*)d_in[2];
    const float* l1 = (const float*)d_in[3];
    const float* o2 = (const float*)d_in[4];
    const float* l2 = (const float*)d_in[5];

    double* accq7 = (double*)d_ws;
    int*    done  = (int*)((char*)d_ws + 24);
    double* slotS = (double*)((char*)d_ws + 64);
    double* slotC = (double*)((char*)d_ws + 14336);
    float4* pbox  = (float4*)((char*)d_ws + 30720);
    float*  noobj = (float*)((char*)d_ws + 1393664);

    mega_a<<<NBLK_A, BDIM, 0, stream>>>(o0, l0, o1, l1, o2, l2,
                                        accq7, done, slotS, slotC, pbox, noobj);
    ignore_fin<<<NB_IGNORE, BDIM, 0, stream>>>(l0, l1, l2,
                                               accq7, done, slotS, slotC,
                                               pbox, noobj, (float*)d_out);
}